// Round 4
// baseline (401.715 us; speedup 1.0000x reference)
//
#include <hip/hip_runtime.h>
#include <math.h>

// T5Attention forward, MI355X/gfx950.
// Pipeline: f32->f16 convert -> QKV GEMMs (fp16 MFMA) -> flash attn w/ rel-pos
// bias + causal + padding mask -> output GEMM (f32 out).

typedef float   f32x4 __attribute__((ext_vector_type(4)));
typedef _Float16 f16x8 __attribute__((ext_vector_type(8)));
typedef _Float16 f16x4 __attribute__((ext_vector_type(4)));

#define GLD16(gp, lp) __builtin_amdgcn_global_load_lds(                       \
    (const __attribute__((address_space(1))) void*)(gp),                      \
    (__attribute__((address_space(3))) void*)(lp), 16, 0, 0)

static constexpr int kB   = 2;
static constexpr int kS   = 2048;
static constexpr int kHID = 1024;
static constexpr int kH   = 16;

// ---------------------------------------------------------------- convert --
__global__ __launch_bounds__(256) void cvt_f32_f16(const float* __restrict__ src,
                                                   _Float16* __restrict__ dst,
                                                   int n) {
  int i = (blockIdx.x * 256 + threadIdx.x) * 4;
  const int stride = gridDim.x * 256 * 4;
  for (; i < n; i += stride) {
    const float4 v = *reinterpret_cast<const float4*>(src + i);
    f16x4 o;
    o[0] = (_Float16)v.x; o[1] = (_Float16)v.y;
    o[2] = (_Float16)v.z; o[3] = (_Float16)v.w;
    *reinterpret_cast<f16x4*>(dst + i) = o;
  }
}

// -------------------------------------------------------------- NT GEMM ----
// C[M,N] = A[M,K] @ W[N,K]^T   (both row-major, K contiguous -> NT layout)
// 128x128 tile, BK=32, 4 waves (2x2 of 64x64), mfma_f32_16x16x32_f16.
template <bool HALF_OUT>
__global__ __launch_bounds__(256) void gemm_nt(const _Float16* __restrict__ A,
                                               const _Float16* __restrict__ W,
                                               void* __restrict__ Cvp,
                                               int M, int N, int K, float scale) {
  __shared__ __align__(16) _Float16 As[128 * 32];
  __shared__ __align__(16) _Float16 Bs[128 * 32];
  const int tid  = threadIdx.x;
  const int lane = tid & 63;
  const int wave = tid >> 6;
  const long bm = (long)blockIdx.y * 128;
  const long bn = (long)blockIdx.x * 128;
  const int wr = (wave >> 1) * 64;   // wave tile origin in block
  const int wc = (wave & 1) * 64;

  // staging: per wave 2 insts for A + 2 for B; lane l -> LDS base + l*16B
  const int srow = wave * 32 + (lane >> 2);
  const int scol = (lane & 3) * 8;
  const _Float16* ga = A + (bm + srow) * (long)K + scol;
  const _Float16* gb = W + (bn + srow) * (long)K + scol;
  _Float16* lA0 = &As[wave * 1024];
  _Float16* lA1 = &As[wave * 1024 + 512];
  _Float16* lB0 = &Bs[wave * 1024];
  _Float16* lB1 = &Bs[wave * 1024 + 512];

  const int lr = lane & 15;          // fragment row/col
  const int lk = (lane >> 4) * 8;    // fragment k offset
  f32x4 acc[4][4] = {};

  for (int k0 = 0; k0 < K; k0 += 32) {
    GLD16(ga + k0, lA0);
    GLD16(ga + k0 + 16 * (long)K, lA1);
    GLD16(gb + k0, lB0);
    GLD16(gb + k0 + 16 * (long)K, lB1);
    __syncthreads();                 // vmcnt drained by compiler before barrier
    f16x8 af[4], bf[4];
#pragma unroll
    for (int i = 0; i < 4; ++i) {
      af[i] = *reinterpret_cast<const f16x8*>(&As[(wr + i * 16 + lr) * 32 + lk]);
      bf[i] = *reinterpret_cast<const f16x8*>(&Bs[(wc + i * 16 + lr) * 32 + lk]);
    }
#pragma unroll
    for (int i = 0; i < 4; ++i)
#pragma unroll
      for (int j = 0; j < 4; ++j)
        acc[i][j] = __builtin_amdgcn_mfma_f32_16x16x32_f16(af[i], bf[j], acc[i][j], 0, 0, 0);
    __syncthreads();                 // reads done before next stage overwrites
  }

  const int cr0 = wr + (lane >> 4) * 4;
  const int cc0 = wc + lr;
#pragma unroll
  for (int i = 0; i < 4; ++i)
#pragma unroll
    for (int j = 0; j < 4; ++j)
#pragma unroll
      for (int r = 0; r < 4; ++r) {
        const long row = bm + cr0 + i * 16 + r;
        const long col = bn + cc0 + j * 16;
        const float v = acc[i][j][r] * scale;
        if (HALF_OUT)
          ((_Float16*)Cvp)[row * N + col] = (_Float16)v;
        else
          ((float*)Cvp)[row * N + col] = v;
      }
}

// ---------------------------------------------------------- flash attention -
// grid (S/64, H, B), block 256 (4 waves x 16 q-rows). K-tiles of 64.
// Q pre-scaled by 1/8. scores = Q'.K + rel_bias; causal + padding mask;
// online softmax; ctx written fp16 to ws.
static constexpr int VLD = 88;   // LDS row stride (halves): 176B, 16B-aligned,
                                 // 2-way bank aliasing on b128 reads (free)

__global__ __launch_bounds__(256) void attn_fwd(const _Float16* __restrict__ Qh,
                                                const _Float16* __restrict__ Kh,
                                                const _Float16* __restrict__ Vh,
                                                const int* __restrict__ maskp,
                                                const float* __restrict__ rel_emb,
                                                _Float16* __restrict__ ctx) {
  __shared__ __align__(16) _Float16 Vt[64 * VLD];  // V transposed: [d][kp]
  __shared__ __align__(16) _Float16 Pl[64 * VLD];  // P: [q_local][kp_local]
  __shared__ float bias_sh[32];
  __shared__ int   kmask[64];

  const int tid  = threadIdx.x;
  const int lane = tid & 63;
  const int wave = tid >> 6;
  const int qt = blockIdx.x, h = blockIdx.y, b = blockIdx.z;
  const int qbase = qt * 64;
  const int lr = lane & 15;
  const int lh = lane >> 4;

  if (tid < 32) bias_sh[tid] = rel_emb[tid * kH + h];

  // Q fragments direct from global (layout == A-operand fragment layout)
  const long qrow = (long)b * kS + qbase + wave * 16 + lr;
  const f16x8 qf0 = *reinterpret_cast<const f16x8*>(&Qh[qrow * kHID + h * 64 + lh * 8]);
  const f16x8 qf1 = *reinterpret_cast<const f16x8*>(&Qh[qrow * kHID + h * 64 + 32 + lh * 8]);

  float mrow[4], lsum[4];
  f32x4 acco[4] = {};
#pragma unroll
  for (int r = 0; r < 4; ++r) { mrow[r] = -INFINITY; lsum[r] = 0.f; }

  const int skp = tid >> 2;        // staging: kp row
  const int sdb = tid & 3;         // staging: d block of 16

  const int ntiles = qt + 1;       // causal
  for (int kt = 0; kt < ntiles; ++kt) {
    const int kbase = kt * 64;
    // ---- stage V transposed + mask tile ----
    {
      const _Float16* vg = &Vh[((long)b * kS + kbase + skp) * kHID + h * 64 + sdb * 16];
      const f16x8 v0 = *reinterpret_cast<const f16x8*>(vg);
      const f16x8 v1 = *reinterpret_cast<const f16x8*>(vg + 8);
#pragma unroll
      for (int j = 0; j < 8; ++j) Vt[(sdb * 16 + j) * VLD + skp] = v0[j];
#pragma unroll
      for (int j = 0; j < 8; ++j) Vt[(sdb * 16 + 8 + j) * VLD + skp] = v1[j];
      if (tid < 64) kmask[tid] = maskp[b * kS + kbase + tid];
    }
    __syncthreads();  // B1: Vt + kmask (+bias on first iter) visible

    // ---- QK^T: S[16 q][64 kp] per wave ----
    f32x4 sacc[4] = {};
#pragma unroll
    for (int nb = 0; nb < 4; ++nb) {
      const long krow = (long)b * kS + kbase + nb * 16 + lr;
      const f16x8 kf0 = *reinterpret_cast<const f16x8*>(&Kh[krow * kHID + h * 64 + lh * 8]);
      const f16x8 kf1 = *reinterpret_cast<const f16x8*>(&Kh[krow * kHID + h * 64 + 32 + lh * 8]);
      sacc[nb] = __builtin_amdgcn_mfma_f32_16x16x32_f16(qf0, kf0, sacc[nb], 0, 0, 0);
      sacc[nb] = __builtin_amdgcn_mfma_f32_16x16x32_f16(qf1, kf1, sacc[nb], 0, 0, 0);
    }

    // ---- online softmax (row = lh*4 + r; 16 lanes/row-group) ----
    float p[4][4];
#pragma unroll
    for (int r = 0; r < 4; ++r) {
      const int q = qbase + wave * 16 + lh * 4 + r;
      float sv[4];
      float tmax = -INFINITY;
#pragma unroll
      for (int nb = 0; nb < 4; ++nb) {
        const int kp = kbase + nb * 16 + lr;
        const bool valid = (kp <= q) && (kmask[nb * 16 + lr] != 0);
        int d = q - kp;
        d = d > 15 ? 15 : d;
        d = d < -16 ? -16 : d;     // clamp both ends -> LDS index in [0,32)
        const float s = valid ? (sacc[nb][r] + bias_sh[d + 16]) : -INFINITY;
        sv[nb] = s;
        tmax = fmaxf(tmax, s);
      }
      for (int xm = 1; xm < 16; xm <<= 1) tmax = fmaxf(tmax, __shfl_xor(tmax, xm, 64));
      const float mnew  = fmaxf(mrow[r], tmax);
      const float alpha = (mnew == -INFINITY) ? 1.0f : __expf(mrow[r] - mnew);
      float rs = 0.f;
#pragma unroll
      for (int nb = 0; nb < 4; ++nb) {
        const float pv = (sv[nb] == -INFINITY) ? 0.f : __expf(sv[nb] - mnew);
        p[nb][r] = pv;
        rs += pv;
      }
      for (int xm = 1; xm < 16; xm <<= 1) rs += __shfl_xor(rs, xm, 64);
      lsum[r] = lsum[r] * alpha + rs;
      mrow[r] = mnew;
#pragma unroll
      for (int nd = 0; nd < 4; ++nd) acco[nd][r] *= alpha;
    }

    // ---- P -> LDS (fp16) ----
#pragma unroll
    for (int nb = 0; nb < 4; ++nb)
#pragma unroll
      for (int r = 0; r < 4; ++r)
        Pl[(wave * 16 + lh * 4 + r) * VLD + nb * 16 + lr] = (_Float16)p[nb][r];
    __syncthreads();  // B2: P visible (and ds_writes drained)

    // ---- PV: ctx[16 q][64 d] += P @ V ----
    const f16x8 pa0 = *reinterpret_cast<const f16x8*>(&Pl[(wave * 16 + lr) * VLD + lh * 8]);
    const f16x8 pa1 = *reinterpret_cast<const f16x8*>(&Pl[(wave * 16 + lr) * VLD + 32 + lh * 8]);
#pragma unroll
    for (int nd = 0; nd < 4; ++nd) {
      const f16x8 bv0 = *reinterpret_cast<const f16x8*>(&Vt[(nd * 16 + lr) * VLD + lh * 8]);
      const f16x8 bv1 = *reinterpret_cast<const f16x8*>(&Vt[(nd * 16 + lr) * VLD + 32 + lh * 8]);
      acco[nd] = __builtin_amdgcn_mfma_f32_16x16x32_f16(pa0, bv0, acco[nd], 0, 0, 0);
      acco[nd] = __builtin_amdgcn_mfma_f32_16x16x32_f16(pa1, bv1, acco[nd], 0, 0, 0);
    }
    __syncthreads();  // B3: PV reads done before next stage overwrites Vt
  }

  // ---- epilogue: ctx = acc / lsum (0 if fully masked == nan_to_num) ----
#pragma unroll
  for (int nd = 0; nd < 4; ++nd)
#pragma unroll
    for (int r = 0; r < 4; ++r) {
      const float den = lsum[r];
      const float v = den > 0.f ? acco[nd][r] / den : 0.f;
      ctx[((long)b * kS + qbase + wave * 16 + lh * 4 + r) * kHID + h * 64 + nd * 16 + lr] =
          (_Float16)v;
    }
}

// ---------------------------------------------------------------- launch ----
extern "C" void kernel_launch(void* const* d_in, const int* in_sizes, int n_in,
                              void* d_out, int out_size, void* d_ws, size_t ws_size,
                              hipStream_t stream) {
  const float* x    = (const float*)d_in[0];
  const int*   mask = (const int*)d_in[1];
  const float* Wq   = (const float*)d_in[2];
  const float* Wk   = (const float*)d_in[3];
  const float* Wv   = (const float*)d_in[4];
  const float* Wo   = (const float*)d_in[5];
  const float* rel  = (const float*)d_in[6];
  float* out = (float*)d_out;

  const int M = kB * kS;          // 4096
  const int NX = M * kHID;        // 4,194,304
  const int NW = kHID * kHID;     // 1,048,576

  _Float16* ws  = (_Float16*)d_ws;
  _Float16* xh  = ws;
  _Float16* wqh = xh + NX;
  _Float16* wkh = wqh + NW;
  _Float16* wvh = wkh + NW;
  _Float16* woh = wvh + NW;
  _Float16* Qh  = woh + NW;
  _Float16* Kh  = Qh + NX;
  _Float16* Vh  = Kh + NX;
  _Float16* ctxh = Vh + NX;       // total 25,165,824 halves = 48 MB

  cvt_f32_f16<<<2048, 256, 0, stream>>>(x, xh, NX);
  cvt_f32_f16<<<1024, 256, 0, stream>>>(Wq, wqh, NW);
  cvt_f32_f16<<<1024, 256, 0, stream>>>(Wk, wkh, NW);
  cvt_f32_f16<<<1024, 256, 0, stream>>>(Wv, wvh, NW);
  cvt_f32_f16<<<1024, 256, 0, stream>>>(Wo, woh, NW);

  dim3 gg(kHID / 128, M / 128);   // (8, 32)
  // fold 1/sqrt(DK)=0.125 into Q
  gemm_nt<true><<<gg, 256, 0, stream>>>(xh, wqh, Qh, M, kHID, kHID, 0.125f);
  gemm_nt<true><<<gg, 256, 0, stream>>>(xh, wkh, Kh, M, kHID, kHID, 1.0f);
  gemm_nt<true><<<gg, 256, 0, stream>>>(xh, wvh, Vh, M, kHID, kHID, 1.0f);

  attn_fwd<<<dim3(kS / 64, kH, kB), 256, 0, stream>>>(Qh, Kh, Vh, mask, rel, ctxh);

  gemm_nt<false><<<gg, 256, 0, stream>>>(ctxh, woh, out, M, kHID, kHID, 1.0f);
}

// Round 5
// 281.315 us; speedup vs baseline: 1.4280x; 1.4280x over previous
//
#include <hip/hip_runtime.h>
#include <math.h>

// T5Attention forward, MI355X/gfx950.  Round 5 structure:
//   cvt x -> f16 ; cvt 4 weights -> f16 (one kernel)
//   fused QKV GEMM (N=3072, 3 blocks/CU), V written TRANSPOSED [B][H][64][S]
//   flash attn: swapped QK^T (P lane-local), Vt staged via swizzled
//     global_load_lds (conflict-free ds_read_b128), 1 barrier/tile,
//     causal-paired q-tiles (uniform 33 tile-units/block)
//   output GEMM (f32 out)

typedef float    f32x4 __attribute__((ext_vector_type(4)));
typedef _Float16 f16x8 __attribute__((ext_vector_type(8)));
typedef _Float16 f16x4 __attribute__((ext_vector_type(4)));

#define GLD16(gp, lp) __builtin_amdgcn_global_load_lds(                       \
    (const __attribute__((address_space(1))) void*)(gp),                      \
    (__attribute__((address_space(3))) void*)(lp), 16, 0, 0)

static constexpr int kB   = 2;
static constexpr int kS   = 2048;
static constexpr int kHID = 1024;
static constexpr int kH   = 16;

// ---------------------------------------------------------------- convert --
__global__ __launch_bounds__(256) void cvt_f32_f16(const float* __restrict__ src,
                                                   _Float16* __restrict__ dst,
                                                   int n) {
  int i = (blockIdx.x * 256 + threadIdx.x) * 4;
  const int stride = gridDim.x * 256 * 4;
  for (; i < n; i += stride) {
    const float4 v = *reinterpret_cast<const float4*>(src + i);
    f16x4 o;
    o[0] = (_Float16)v.x; o[1] = (_Float16)v.y;
    o[2] = (_Float16)v.z; o[3] = (_Float16)v.w;
    *reinterpret_cast<f16x4*>(dst + i) = o;
  }
}

// 4 weight matrices (1M elements each) -> contiguous f16 dst
__global__ __launch_bounds__(256) void cvt_w4(const float* __restrict__ w0,
                                              const float* __restrict__ w1,
                                              const float* __restrict__ w2,
                                              const float* __restrict__ w3,
                                              _Float16* __restrict__ dst) {
  const int wsel = blockIdx.x >> 8;            // 256 blocks per weight
  const float* src = wsel == 0 ? w0 : wsel == 1 ? w1 : wsel == 2 ? w2 : w3;
  _Float16* d = dst + (long)wsel * 1048576;
  const int base = (blockIdx.x & 255) * 4096;
#pragma unroll
  for (int it = 0; it < 4; ++it) {
    const int i = base + it * 1024 + threadIdx.x * 4;
    const float4 v = *reinterpret_cast<const float4*>(src + i);
    f16x4 o;
    o[0] = (_Float16)v.x; o[1] = (_Float16)v.y;
    o[2] = (_Float16)v.z; o[3] = (_Float16)v.w;
    *reinterpret_cast<f16x4*>(d + i) = o;
  }
}

// ------------------------------------------------------- fused QKV GEMM ----
// C[M=4096, N=3072] = x @ [Wq;Wk;Wv]^T.  128x128 tile, BK=32, 4 waves.
// cols [0,1024): Q (scaled 1/8) ; [1024,2048): K ; [2048,3072): V written
// transposed into Vtg[b][h][d][s].
__global__ __launch_bounds__(256) void gemm_qkv(const _Float16* __restrict__ A,
                                                const _Float16* __restrict__ W,
                                                _Float16* __restrict__ Qh,
                                                _Float16* __restrict__ Kh,
                                                _Float16* __restrict__ Vtg) {
  constexpr int K = kHID;
  __shared__ __align__(16) _Float16 As[128 * 32];
  __shared__ __align__(16) _Float16 Bs[128 * 32];
  const int tid  = threadIdx.x;
  const int lane = tid & 63;
  const int wave = tid >> 6;
  const long bm = (long)blockIdx.y * 128;
  const long bn = (long)blockIdx.x * 128;
  const int wr = (wave >> 1) * 64;
  const int wc = (wave & 1) * 64;

  const int srow = wave * 32 + (lane >> 2);
  const int scol = (lane & 3) * 8;
  const _Float16* ga = A + (bm + srow) * (long)K + scol;
  const _Float16* gb = W + (bn + srow) * (long)K + scol;
  _Float16* lA0 = &As[wave * 1024];
  _Float16* lA1 = &As[wave * 1024 + 512];
  _Float16* lB0 = &Bs[wave * 1024];
  _Float16* lB1 = &Bs[wave * 1024 + 512];

  const int lr = lane & 15;
  const int lk = (lane >> 4) * 8;
  f32x4 acc[4][4] = {};

  for (int k0 = 0; k0 < K; k0 += 32) {
    GLD16(ga + k0, lA0);
    GLD16(ga + k0 + 16 * (long)K, lA1);
    GLD16(gb + k0, lB0);
    GLD16(gb + k0 + 16 * (long)K, lB1);
    __syncthreads();
    f16x8 af[4], bf[4];
#pragma unroll
    for (int i = 0; i < 4; ++i) {
      af[i] = *reinterpret_cast<const f16x8*>(&As[(wr + i * 16 + lr) * 32 + lk]);
      bf[i] = *reinterpret_cast<const f16x8*>(&Bs[(wc + i * 16 + lr) * 32 + lk]);
    }
#pragma unroll
    for (int i = 0; i < 4; ++i)
#pragma unroll
      for (int j = 0; j < 4; ++j)
        acc[i][j] = __builtin_amdgcn_mfma_f32_16x16x32_f16(af[i], bf[j], acc[i][j], 0, 0, 0);
    __syncthreads();
  }

  const int cr0 = wr + (lane >> 4) * 4;
  const int cc0 = wc + lr;
  const int cb = (int)(bn >> 10);          // 0=Q 1=K 2=V (block-uniform)
#pragma unroll
  for (int i = 0; i < 4; ++i)
#pragma unroll
    for (int j = 0; j < 4; ++j)
#pragma unroll
      for (int r = 0; r < 4; ++r) {
        const long row = bm + cr0 + i * 16 + r;       // token index
        const int  col = (int)bn + cc0 + j * 16;      // 0..3071
        const float v = acc[i][j][r];
        if (cb == 0) {
          Qh[row * kHID + col] = (_Float16)(v * 0.125f);
        } else if (cb == 1) {
          Kh[row * kHID + (col - 1024)] = (_Float16)v;
        } else {
          const int hid = col - 2048;
          const int hh = hid >> 6, dd = hid & 63;
          const int bb = (int)(row >> 11), sp = (int)(row & 2047);
          Vtg[((long)(bb * kH + hh) * 64 + dd) * kS + sp] = (_Float16)v;
        }
      }
}

// ---------------------------------------------------------- flash attention -
// grid (16, H, B) block 256.  Block handles q-tiles {i, 31-i} (33 tile-units).
// Swapped QK^T: sacc[nb][r] = S[kp=kbase+nb*16+lh*4+r][q=qbase+wave*16+lr].
// Vt tile [d=64][kc=64] staged via global_load_lds with XOR swizzle
// (16B chunk c of row d holds kc-group c^(d&7)) -> conflict-free b128 reads.
__global__ __launch_bounds__(256) void attn_fwd2(const _Float16* __restrict__ Qh,
                                                 const _Float16* __restrict__ Kh,
                                                 const _Float16* __restrict__ Vtg,
                                                 const int* __restrict__ maskp,
                                                 const float* __restrict__ rel_emb,
                                                 _Float16* __restrict__ ctx) {
  __shared__ __align__(16) _Float16 Vt[2][64 * 64];
  __shared__ int   kmask2[2][64];
  __shared__ float bias_sh[32];

  const int tid  = threadIdx.x;
  const int lane = tid & 63;
  const int wave = tid >> 6;
  const int h = blockIdx.y, b = blockIdx.z;
  const int lr = lane & 15;
  const int lh = lane >> 4;

  if (tid < 32) bias_sh[tid] = rel_emb[tid * kH + h];

  // staging addresses (lane-fixed): inst t covers rows wave*16 + t*8 + (lane>>3)
  const long bh64 = (long)(b * kH + h) * 64;
  const int  skc  = ((lane & 7) ^ (lane >> 3)) * 8;   // pre-swizzled kc origin
  const _Float16* vsrc0 = Vtg + (bh64 + wave * 16 + (lane >> 3)) * kS + skc;
  const _Float16* vsrc1 = vsrc0 + 8 * kS;

  for (int pass = 0; pass < 2; ++pass) {
    const int qt = (pass == 0) ? (int)blockIdx.x : 31 - (int)blockIdx.x;
    const int qbase = qt * 64;

    const long qrow = (long)b * kS + qbase + wave * 16 + lr;
    const f16x8 qf0 = *reinterpret_cast<const f16x8*>(&Qh[qrow * kHID + h * 64 + lh * 8]);
    const f16x8 qf1 = *reinterpret_cast<const f16x8*>(&Qh[qrow * kHID + h * 64 + 32 + lh * 8]);

    float m = -INFINITY, lsum = 0.f;
    f32x4 acco[4] = {};

    // prologue: stage tile 0 -> buf 0
    GLD16(vsrc0, &Vt[0][wave * 1024]);
    GLD16(vsrc1, &Vt[0][wave * 1024 + 512]);
    if (tid < 64) kmask2[0][tid] = maskp[b * kS + tid];
    __syncthreads();

    const int ntiles = qt + 1;
    for (int kt = 0; kt < ntiles; ++kt) {
      const int cur = kt & 1;
      const int kbase = kt * 64;
      if (kt + 1 < ntiles) {                 // prefetch next tile
        GLD16(vsrc0 + kbase + 64, &Vt[cur ^ 1][wave * 1024]);
        GLD16(vsrc1 + kbase + 64, &Vt[cur ^ 1][wave * 1024 + 512]);
        if (tid < 64) kmask2[cur ^ 1][tid] = maskp[b * kS + kbase + 64 + tid];
      }
      // ---- QK^T (swapped) ----
      f32x4 sacc[4] = {};
#pragma unroll
      for (int nb = 0; nb < 4; ++nb) {
        const _Float16* kr = &Kh[((long)b * kS + kbase + nb * 16 + lr) * kHID + h * 64 + lh * 8];
        const f16x8 kf0 = *reinterpret_cast<const f16x8*>(kr);
        const f16x8 kf1 = *reinterpret_cast<const f16x8*>(kr + 32);
        sacc[nb] = __builtin_amdgcn_mfma_f32_16x16x32_f16(kf0, qf0, sacc[nb], 0, 0, 0);
        sacc[nb] = __builtin_amdgcn_mfma_f32_16x16x32_f16(kf1, qf1, sacc[nb], 0, 0, 0);
      }
      // ---- bias + causal + mask; softmax over column q = qbase+wave*16+lr ----
      const int q = qbase + wave * 16 + lr;
      float sv[4][4];
      float tmax = -INFINITY;
#pragma unroll
      for (int nb = 0; nb < 4; ++nb)
#pragma unroll
        for (int r = 0; r < 4; ++r) {
          const int kp = kbase + nb * 16 + lh * 4 + r;
          const bool valid = (kp <= q) && (kmask2[cur][nb * 16 + lh * 4 + r] != 0);
          int d = q - kp;
          d = d > 15 ? 15 : d;
          d = d < -16 ? -16 : d;
          const float s = sacc[nb][r] + bias_sh[d + 16];
          sv[nb][r] = valid ? s : -INFINITY;
          tmax = fmaxf(tmax, sv[nb][r]);
        }
      tmax = fmaxf(tmax, __shfl_xor(tmax, 16, 64));
      tmax = fmaxf(tmax, __shfl_xor(tmax, 32, 64));
      const float mnew  = fmaxf(m, tmax);
      const float alpha = (mnew == -INFINITY) ? 1.f : __expf(m - mnew);
      float p[4][4];
      float rs = 0.f;
#pragma unroll
      for (int nb = 0; nb < 4; ++nb)
#pragma unroll
        for (int r = 0; r < 4; ++r) {
          const float pv = (sv[nb][r] == -INFINITY) ? 0.f : __expf(sv[nb][r] - mnew);
          p[nb][r] = pv;
          rs += pv;
        }
      rs += __shfl_xor(rs, 16, 64);
      rs += __shfl_xor(rs, 32, 64);
      lsum = lsum * alpha + rs;
      m = mnew;
      // rescale acco: row q' = lh*4+r needs alpha of that column (lane lh*4+r)
      float alq[4];
#pragma unroll
      for (int r = 0; r < 4; ++r) alq[r] = __shfl(alpha, lh * 4 + r, 64);
#pragma unroll
      for (int nd = 0; nd < 4; ++nd) {
        acco[nd][0] *= alq[0]; acco[nd][1] *= alq[1];
        acco[nd][2] *= alq[2]; acco[nd][3] *= alq[3];
      }
      // ---- pack P to fp16 + redistribute to PV A-frag layout ----
      // source: P[kp'][q=lr] at lane (lh_s=(kp'>>2)&3, lr), reg (r=kp'&3, nb=kp'>>4)
      // target lane (lh2,lr2) frag s: kp' = 32s + lh2*8 + j
      int pk[4][2];
#pragma unroll
      for (int nb = 0; nb < 4; ++nb) {
        pk[nb][0] = __builtin_bit_cast(int, __builtin_amdgcn_cvt_pkrtz(p[nb][0], p[nb][1]));
        pk[nb][1] = __builtin_bit_cast(int, __builtin_amdgcn_cvt_pkrtz(p[nb][2], p[nb][3]));
      }
      const int srcA = (((lh * 2) & 3) << 4) | lr;
      const int srcB = (((lh * 2 + 1) & 3) << 4) | lr;
      const bool lo = lh < 2;                 // nb = 2s + (lh>>1)
      int4 w0, w1;
      {
        int a0 = __shfl(pk[0][0], srcA, 64), b0 = __shfl(pk[1][0], srcA, 64);
        int a1 = __shfl(pk[0][1], srcA, 64), b1 = __shfl(pk[1][1], srcA, 64);
        int a2 = __shfl(pk[0][0], srcB, 64), b2 = __shfl(pk[1][0], srcB, 64);
        int a3 = __shfl(pk[0][1], srcB, 64), b3 = __shfl(pk[1][1], srcB, 64);
        w0.x = lo ? a0 : b0; w0.y = lo ? a1 : b1;
        w0.z = lo ? a2 : b2; w0.w = lo ? a3 : b3;
        a0 = __shfl(pk[2][0], srcA, 64); b0 = __shfl(pk[3][0], srcA, 64);
        a1 = __shfl(pk[2][1], srcA, 64); b1 = __shfl(pk[3][1], srcA, 64);
        a2 = __shfl(pk[2][0], srcB, 64); b2 = __shfl(pk[3][0], srcB, 64);
        a3 = __shfl(pk[2][1], srcB, 64); b3 = __shfl(pk[3][1], srcB, 64);
        w1.x = lo ? a0 : b0; w1.y = lo ? a1 : b1;
        w1.z = lo ? a2 : b2; w1.w = lo ? a3 : b3;
      }
      const f16x8 pa0 = *reinterpret_cast<const f16x8*>(&w0);
      const f16x8 pa1 = *reinterpret_cast<const f16x8*>(&w1);
      // ---- PV from swizzled Vt: B-frag row d = nd*16+lr, k = kp0 + lh*8 + j ----
      const char* vb = (const char*)&Vt[cur][0];
      const int xa = ((lh ^ (lane & 7)) << 4);
      const int xb = (((4 + lh) ^ (lane & 7)) << 4);
#pragma unroll
      for (int nd = 0; nd < 4; ++nd) {
        const int rowb = (nd * 16 + lr) * 128;
        const f16x8 bv0 = *reinterpret_cast<const f16x8*>(vb + rowb + xa);
        const f16x8 bv1 = *reinterpret_cast<const f16x8*>(vb + rowb + xb);
        acco[nd] = __builtin_amdgcn_mfma_f32_16x16x32_f16(pa0, bv0, acco[nd], 0, 0, 0);
        acco[nd] = __builtin_amdgcn_mfma_f32_16x16x32_f16(pa1, bv1, acco[nd], 0, 0, 0);
      }
      __syncthreads();   // PV reads done; prefetch (vmcnt) drained for next tile
    }
    // ---- epilogue: lane holds ctx[q=lh*4+r][d=nd*16+lr] ----
    float lsq[4];
#pragma unroll
    for (int r = 0; r < 4; ++r) lsq[r] = __shfl(lsum, lh * 4 + r, 64);
#pragma unroll
    for (int nd = 0; nd < 4; ++nd)
#pragma unroll
      for (int r = 0; r < 4; ++r) {
        const float den = lsq[r];
        const float v = den > 0.f ? acco[nd][r] / den : 0.f;
        ctx[((long)b * kS + qbase + wave * 16 + lh * 4 + r) * kHID + h * 64 + nd * 16 + lr] =
            (_Float16)v;
      }
  }
}

// -------------------------------------------------------------- NT GEMM ----
// (output projection) C[M,N] = A[M,K] @ W[N,K]^T, f32 out.
__global__ __launch_bounds__(256) void gemm_out(const _Float16* __restrict__ A,
                                                const _Float16* __restrict__ W,
                                                float* __restrict__ C,
                                                int M, int N, int K) {
  __shared__ __align__(16) _Float16 As[128 * 32];
  __shared__ __align__(16) _Float16 Bs[128 * 32];
  const int tid  = threadIdx.x;
  const int lane = tid & 63;
  const int wave = tid >> 6;
  const long bm = (long)blockIdx.y * 128;
  const long bn = (long)blockIdx.x * 128;
  const int wr = (wave >> 1) * 64;
  const int wc = (wave & 1) * 64;

  const int srow = wave * 32 + (lane >> 2);
  const int scol = (lane & 3) * 8;
  const _Float16* ga = A + (bm + srow) * (long)K + scol;
  const _Float16* gb = W + (bn + srow) * (long)K + scol;
  _Float16* lA0 = &As[wave * 1024];
  _Float16* lA1 = &As[wave * 1024 + 512];
  _Float16* lB0 = &Bs[wave * 1024];
  _Float16* lB1 = &Bs[wave * 1024 + 512];

  const int lr = lane & 15;
  const int lk = (lane >> 4) * 8;
  f32x4 acc[4][4] = {};

  for (int k0 = 0; k0 < K; k0 += 32) {
    GLD16(ga + k0, lA0);
    GLD16(ga + k0 + 16 * (long)K, lA1);
    GLD16(gb + k0, lB0);
    GLD16(gb + k0 + 16 * (long)K, lB1);
    __syncthreads();
    f16x8 af[4], bf[4];
#pragma unroll
    for (int i = 0; i < 4; ++i) {
      af[i] = *reinterpret_cast<const f16x8*>(&As[(wr + i * 16 + lr) * 32 + lk]);
      bf[i] = *reinterpret_cast<const f16x8*>(&Bs[(wc + i * 16 + lr) * 32 + lk]);
    }
#pragma unroll
    for (int i = 0; i < 4; ++i)
#pragma unroll
      for (int j = 0; j < 4; ++j)
        acc[i][j] = __builtin_amdgcn_mfma_f32_16x16x32_f16(af[i], bf[j], acc[i][j], 0, 0, 0);
    __syncthreads();
  }

  const int cr0 = wr + (lane >> 4) * 4;
  const int cc0 = wc + lr;
#pragma unroll
  for (int i = 0; i < 4; ++i)
#pragma unroll
    for (int j = 0; j < 4; ++j)
#pragma unroll
      for (int r = 0; r < 4; ++r)
        C[(bm + cr0 + i * 16 + r) * N + bn + cc0 + j * 16] = acc[i][j][r];
}

// ---------------------------------------------------------------- launch ----
extern "C" void kernel_launch(void* const* d_in, const int* in_sizes, int n_in,
                              void* d_out, int out_size, void* d_ws, size_t ws_size,
                              hipStream_t stream) {
  const float* x    = (const float*)d_in[0];
  const int*   mask = (const int*)d_in[1];
  const float* Wq   = (const float*)d_in[2];
  const float* Wk   = (const float*)d_in[3];
  const float* Wv   = (const float*)d_in[4];
  const float* Wo   = (const float*)d_in[5];
  const float* rel  = (const float*)d_in[6];
  float* out = (float*)d_out;

  const int M = kB * kS;          // 4096
  const int NX = M * kHID;        // 4,194,304
  const int NW = kHID * kHID;     // 1,048,576

  _Float16* ws   = (_Float16*)d_ws;
  _Float16* xh   = ws;
  _Float16* wqh  = xh + NX;       // wq,wk,wv,wo contiguous (3072+1024 rows)
  _Float16* woh  = wqh + 3 * NW;
  _Float16* Qh   = woh + NW;
  _Float16* Kh   = Qh + NX;
  _Float16* Vtg  = Kh + NX;       // [B][H][64][S] transposed V
  _Float16* ctxh = Vtg + NX;      // total 24M halves = 48 MB

  cvt_f32_f16<<<2048, 256, 0, stream>>>(x, xh, NX);
  cvt_w4<<<1024, 256, 0, stream>>>(Wq, Wk, Wv, Wo, wqh);

  gemm_qkv<<<dim3(24, 32), 256, 0, stream>>>(xh, wqh, Qh, Kh, Vtg);

  attn_fwd2<<<dim3(16, kH, kB), 256, 0, stream>>>(Qh, Kh, Vtg, mask, rel, ctxh);

  gemm_out<<<dim3(8, 32), 256, 0, stream>>>(ctxh, woh, out, M, kHID, kHID);
}

// Round 6
// 221.144 us; speedup vs baseline: 1.8165x; 1.2721x over previous
//
#include <hip/hip_runtime.h>
#include <math.h>

// T5Attention forward, MI355X/gfx950.  Round 6 structure:
//   cvt x/weights -> f16 ; prep_mask (tile-valid bitmask + f32 mask bias)
//   fused QKV GEMM (N=3072), V written TRANSPOSED [B][H][64][S]
//   flash attn: K AND V tiles staged via swizzled global_load_lds
//     (double-buffered, prefetch at tile top), swapped QK^T, fast-path
//     softmax for sub-diagonal tiles, XCD-clustered block swizzle,
//     causal-paired q-tiles (uniform 33 tile-units/block)
//   output GEMM (f32 out)

typedef float    f32x4 __attribute__((ext_vector_type(4)));
typedef _Float16 f16x8 __attribute__((ext_vector_type(8)));
typedef _Float16 f16x4 __attribute__((ext_vector_type(4)));

#define GLD16(gp, lp) __builtin_amdgcn_global_load_lds(                       \
    (const __attribute__((address_space(1))) void*)(gp),                      \
    (__attribute__((address_space(3))) void*)(lp), 16, 0, 0)

static constexpr int kB   = 2;
static constexpr int kS   = 2048;
static constexpr int kHID = 1024;
static constexpr int kH   = 16;

// ---------------------------------------------------------------- convert --
__global__ __launch_bounds__(256) void cvt_f32_f16(const float* __restrict__ src,
                                                   _Float16* __restrict__ dst,
                                                   int n) {
  int i = (blockIdx.x * 256 + threadIdx.x) * 4;
  const int stride = gridDim.x * 256 * 4;
  for (; i < n; i += stride) {
    const float4 v = *reinterpret_cast<const float4*>(src + i);
    f16x4 o;
    o[0] = (_Float16)v.x; o[1] = (_Float16)v.y;
    o[2] = (_Float16)v.z; o[3] = (_Float16)v.w;
    *reinterpret_cast<f16x4*>(dst + i) = o;
  }
}

__global__ __launch_bounds__(256) void cvt_w4(const float* __restrict__ w0,
                                              const float* __restrict__ w1,
                                              const float* __restrict__ w2,
                                              const float* __restrict__ w3,
                                              _Float16* __restrict__ dst) {
  const int wsel = blockIdx.x >> 8;
  const float* src = wsel == 0 ? w0 : wsel == 1 ? w1 : wsel == 2 ? w2 : w3;
  _Float16* d = dst + (long)wsel * 1048576;
  const int base = (blockIdx.x & 255) * 4096;
#pragma unroll
  for (int it = 0; it < 4; ++it) {
    const int i = base + it * 1024 + threadIdx.x * 4;
    const float4 v = *reinterpret_cast<const float4*>(src + i);
    f16x4 o;
    o[0] = (_Float16)v.x; o[1] = (_Float16)v.y;
    o[2] = (_Float16)v.z; o[3] = (_Float16)v.w;
    *reinterpret_cast<f16x4*>(d + i) = o;
  }
}

// ------------------------------------------------------------- mask prep ---
// per batch b: tileflags[b] bit t = all 64 positions of k-tile t valid;
// maskbias[b][kp] = valid ? 0 : -inf.
__global__ __launch_bounds__(256) void prep_mask(const int* __restrict__ maskp,
                                                 float* __restrict__ maskbias,
                                                 unsigned int* __restrict__ tileflags) {
  const int b = blockIdx.x;
  const int tid = threadIdx.x;
  const int wave = tid >> 6, lane = tid & 63;
  __shared__ unsigned int partial[4];
  unsigned int mybits = 0;
#pragma unroll
  for (int it = 0; it < 8; ++it) {
    const int t = it * 4 + wave;
    const int kp = t * 64 + lane;
    const int mv = maskp[b * kS + kp];
    maskbias[b * kS + kp] = mv ? 0.f : -INFINITY;
    const unsigned long long bal = __ballot(mv != 0);
    if (bal == ~0ull) mybits |= (1u << t);
  }
  if (lane == 0) partial[wave] = mybits;
  __syncthreads();
  if (tid == 0) tileflags[b] = partial[0] | partial[1] | partial[2] | partial[3];
}

// ------------------------------------------------------- fused QKV GEMM ----
__global__ __launch_bounds__(256) void gemm_qkv(const _Float16* __restrict__ A,
                                                const _Float16* __restrict__ W,
                                                _Float16* __restrict__ Qh,
                                                _Float16* __restrict__ Kh,
                                                _Float16* __restrict__ Vtg) {
  constexpr int K = kHID;
  __shared__ __align__(16) _Float16 As[128 * 32];
  __shared__ __align__(16) _Float16 Bs[128 * 32];
  const int tid  = threadIdx.x;
  const int lane = tid & 63;
  const int wave = tid >> 6;
  const long bm = (long)blockIdx.y * 128;
  const long bn = (long)blockIdx.x * 128;
  const int wr = (wave >> 1) * 64;
  const int wc = (wave & 1) * 64;

  const int srow = wave * 32 + (lane >> 2);
  const int scol = (lane & 3) * 8;
  const _Float16* ga = A + (bm + srow) * (long)K + scol;
  const _Float16* gb = W + (bn + srow) * (long)K + scol;
  _Float16* lA0 = &As[wave * 1024];
  _Float16* lA1 = &As[wave * 1024 + 512];
  _Float16* lB0 = &Bs[wave * 1024];
  _Float16* lB1 = &Bs[wave * 1024 + 512];

  const int lr = lane & 15;
  const int lk = (lane >> 4) * 8;
  f32x4 acc[4][4] = {};

  for (int k0 = 0; k0 < K; k0 += 32) {
    GLD16(ga + k0, lA0);
    GLD16(ga + k0 + 16 * (long)K, lA1);
    GLD16(gb + k0, lB0);
    GLD16(gb + k0 + 16 * (long)K, lB1);
    __syncthreads();
    f16x8 af[4], bf[4];
#pragma unroll
    for (int i = 0; i < 4; ++i) {
      af[i] = *reinterpret_cast<const f16x8*>(&As[(wr + i * 16 + lr) * 32 + lk]);
      bf[i] = *reinterpret_cast<const f16x8*>(&Bs[(wc + i * 16 + lr) * 32 + lk]);
    }
#pragma unroll
    for (int i = 0; i < 4; ++i)
#pragma unroll
      for (int j = 0; j < 4; ++j)
        acc[i][j] = __builtin_amdgcn_mfma_f32_16x16x32_f16(af[i], bf[j], acc[i][j], 0, 0, 0);
    __syncthreads();
  }

  const int cr0 = wr + (lane >> 4) * 4;
  const int cc0 = wc + lr;
  const int cb = (int)(bn >> 10);          // 0=Q 1=K 2=V (block-uniform)
#pragma unroll
  for (int i = 0; i < 4; ++i)
#pragma unroll
    for (int j = 0; j < 4; ++j)
#pragma unroll
      for (int r = 0; r < 4; ++r) {
        const long row = bm + cr0 + i * 16 + r;       // token index
        const int  col = (int)bn + cc0 + j * 16;      // 0..3071
        const float v = acc[i][j][r];
        if (cb == 0) {
          Qh[row * kHID + col] = (_Float16)(v * 0.125f);
        } else if (cb == 1) {
          Kh[row * kHID + (col - 1024)] = (_Float16)v;
        } else {
          const int hid = col - 2048;
          const int hh = hid >> 6, dd = hid & 63;
          const int bb = (int)(row >> 11), sp = (int)(row & 2047);
          Vtg[((long)(bb * kH + hh) * 64 + dd) * kS + sp] = (_Float16)v;
        }
      }
}

// ---------------------------------------------------------- flash attention -
// 1D grid 512, block 256.  XCD-clustered swizzle: each (b,h) pair lives on one
// XCD.  Block handles q-tiles {i, 31-i} (33 tile-units).  K and V tiles staged
// double-buffered via swizzled global_load_lds: LDS[row][c] = G[row][c^(row&7)]
// (chunks of 8 halves) -> conflict-free ds_read_b128 fragment reads.
__global__ __launch_bounds__(256) void attn_fwd3(const _Float16* __restrict__ Qh,
                                                 const _Float16* __restrict__ Kh,
                                                 const _Float16* __restrict__ Vtg,
                                                 const float* __restrict__ maskbias,
                                                 const unsigned int* __restrict__ tileflags,
                                                 const float* __restrict__ rel_emb,
                                                 _Float16* __restrict__ ctx) {
  __shared__ __align__(16) _Float16 Kt[2][64 * 64];
  __shared__ __align__(16) _Float16 Vt[2][64 * 64];
  __shared__ float bias_sh[32];

  const int tid  = threadIdx.x;
  const int lane = tid & 63;
  const int wave = tid >> 6;
  // XCD-clustered bijective swizzle (xcd = bid%8 round-robin assumption)
  const int o = blockIdx.x;
  const int slot = o >> 3;
  const int p = (o & 7) + 8 * (slot >> 4);   // (b,h) group 0..31
  const int qp = slot & 15;                  // q pair 0..15
  const int b = p >> 4, h = p & 15;

  const int lr = lane & 15;
  const int lh = lane >> 4;

  if (tid < 32) bias_sh[tid] = rel_emb[tid * kH + h];
  const unsigned int flags = tileflags[b];

  // staging addresses (lane-fixed). row&7 == lane>>3 for both K and V.
  const int srow8  = lane >> 3;
  const int schunk = (lane & 7) ^ srow8;
  const _Float16* ksrc0 = Kh + ((long)b * kS + wave * 16 + srow8) * kHID + h * 64 + schunk * 8;
  const _Float16* ksrc1 = ksrc0 + 8 * kHID;
  const long bh64 = (long)(b * kH + h) * 64;
  const _Float16* vsrc0 = Vtg + (bh64 + wave * 16 + srow8) * kS + schunk * 8;
  const _Float16* vsrc1 = vsrc0 + 8 * kS;

  for (int pass = 0; pass < 2; ++pass) {
    const int qt = (pass == 0) ? qp : 31 - qp;
    const int qbase = qt * 64;

    const long qrow = (long)b * kS + qbase + wave * 16 + lr;
    const f16x8 qf0 = *reinterpret_cast<const f16x8*>(&Qh[qrow * kHID + h * 64 + lh * 8]);
    const f16x8 qf1 = *reinterpret_cast<const f16x8*>(&Qh[qrow * kHID + h * 64 + 32 + lh * 8]);

    float m = -INFINITY, lsum = 0.f;
    f32x4 acco[4] = {};

    // prologue: stage tile 0 -> buf 0
    GLD16(ksrc0, &Kt[0][wave * 1024]);
    GLD16(ksrc1, &Kt[0][wave * 1024 + 512]);
    GLD16(vsrc0, &Vt[0][wave * 1024]);
    GLD16(vsrc1, &Vt[0][wave * 1024 + 512]);
    __syncthreads();

    const int ntiles = qt + 1;
    for (int kt = 0; kt < ntiles; ++kt) {
      const int cur = kt & 1;
      const int kbase = kt * 64;
      if (kt + 1 < ntiles) {                 // prefetch next tile (async)
        GLD16(ksrc0 + (long)(kbase + 64) * kHID, &Kt[cur ^ 1][wave * 1024]);
        GLD16(ksrc1 + (long)(kbase + 64) * kHID, &Kt[cur ^ 1][wave * 1024 + 512]);
        GLD16(vsrc0 + kbase + 64, &Vt[cur ^ 1][wave * 1024]);
        GLD16(vsrc1 + kbase + 64, &Vt[cur ^ 1][wave * 1024 + 512]);
      }
      // ---- QK^T (swapped) from LDS K tile ----
      const char* kb_ = (const char*)&Kt[cur][0];
      const int xa = ((lh ^ (lr & 7)) << 4);
      const int xb = (((4 + lh) ^ (lr & 7)) << 4);
      f32x4 sacc[4] = {};
#pragma unroll
      for (int nb = 0; nb < 4; ++nb) {
        const int rowb = (nb * 16 + lr) * 128;
        const f16x8 kf0 = *reinterpret_cast<const f16x8*>(kb_ + rowb + xa);
        const f16x8 kf1 = *reinterpret_cast<const f16x8*>(kb_ + rowb + xb);
        sacc[nb] = __builtin_amdgcn_mfma_f32_16x16x32_f16(kf0, qf0, sacc[nb], 0, 0, 0);
        sacc[nb] = __builtin_amdgcn_mfma_f32_16x16x32_f16(kf1, qf1, sacc[nb], 0, 0, 0);
      }
      // ---- softmax over column q (lane lr); fast path for sub-diag tiles ----
      const int q = qbase + wave * 16 + lr;
      const bool tilevalid = (flags >> kt) & 1u;
      float sv[4][4];
      float tmax = -INFINITY;
      if (kt <= qt - 2 && tilevalid) {
        const float b31 = bias_sh[31];
#pragma unroll
        for (int nb = 0; nb < 4; ++nb)
#pragma unroll
          for (int r = 0; r < 4; ++r) {
            sv[nb][r] = sacc[nb][r] + b31;
            tmax = fmaxf(tmax, sv[nb][r]);
          }
      } else {
#pragma unroll
        for (int nb = 0; nb < 4; ++nb)
#pragma unroll
          for (int r = 0; r < 4; ++r) {
            const int kp = kbase + nb * 16 + lh * 4 + r;
            const float mb = tilevalid ? 0.f : maskbias[b * kS + kp];
            int d = q - kp;
            d = d > 15 ? 15 : d;
            d = d < -16 ? -16 : d;
            const float s = sacc[nb][r] + bias_sh[d + 16] + mb;
            sv[nb][r] = (kp <= q) ? s : -INFINITY;
            tmax = fmaxf(tmax, sv[nb][r]);
          }
      }
      tmax = fmaxf(tmax, __shfl_xor(tmax, 16, 64));
      tmax = fmaxf(tmax, __shfl_xor(tmax, 32, 64));
      const float mnew  = fmaxf(m, tmax);
      const float alpha = (mnew == -INFINITY) ? 1.f : __expf(m - mnew);
      float p[4][4];
      float rs = 0.f;
#pragma unroll
      for (int nb = 0; nb < 4; ++nb)
#pragma unroll
        for (int r = 0; r < 4; ++r) {
          const float pv = (sv[nb][r] == -INFINITY) ? 0.f : __expf(sv[nb][r] - mnew);
          p[nb][r] = pv;
          rs += pv;
        }
      rs += __shfl_xor(rs, 16, 64);
      rs += __shfl_xor(rs, 32, 64);
      lsum = lsum * alpha + rs;
      m = mnew;
      float alq[4];
#pragma unroll
      for (int r = 0; r < 4; ++r) alq[r] = __shfl(alpha, lh * 4 + r, 64);
#pragma unroll
      for (int nd = 0; nd < 4; ++nd) {
        acco[nd][0] *= alq[0]; acco[nd][1] *= alq[1];
        acco[nd][2] *= alq[2]; acco[nd][3] *= alq[3];
      }
      // ---- pack P to fp16 + redistribute to PV A-frag layout (validated) ----
      int pk[4][2];
#pragma unroll
      for (int nb = 0; nb < 4; ++nb) {
        pk[nb][0] = __builtin_bit_cast(int, __builtin_amdgcn_cvt_pkrtz(p[nb][0], p[nb][1]));
        pk[nb][1] = __builtin_bit_cast(int, __builtin_amdgcn_cvt_pkrtz(p[nb][2], p[nb][3]));
      }
      const int srcA = (((lh * 2) & 3) << 4) | lr;
      const int srcB = (((lh * 2 + 1) & 3) << 4) | lr;
      const bool lo = lh < 2;
      int4 w0, w1;
      {
        int a0 = __shfl(pk[0][0], srcA, 64), b0 = __shfl(pk[1][0], srcA, 64);
        int a1 = __shfl(pk[0][1], srcA, 64), b1 = __shfl(pk[1][1], srcA, 64);
        int a2 = __shfl(pk[0][0], srcB, 64), b2 = __shfl(pk[1][0], srcB, 64);
        int a3 = __shfl(pk[0][1], srcB, 64), b3 = __shfl(pk[1][1], srcB, 64);
        w0.x = lo ? a0 : b0; w0.y = lo ? a1 : b1;
        w0.z = lo ? a2 : b2; w0.w = lo ? a3 : b3;
        a0 = __shfl(pk[2][0], srcA, 64); b0 = __shfl(pk[3][0], srcA, 64);
        a1 = __shfl(pk[2][1], srcA, 64); b1 = __shfl(pk[3][1], srcA, 64);
        a2 = __shfl(pk[2][0], srcB, 64); b2 = __shfl(pk[3][0], srcB, 64);
        a3 = __shfl(pk[2][1], srcB, 64); b3 = __shfl(pk[3][1], srcB, 64);
        w1.x = lo ? a0 : b0; w1.y = lo ? a1 : b1;
        w1.z = lo ? a2 : b2; w1.w = lo ? a3 : b3;
      }
      const f16x8 pa0 = *reinterpret_cast<const f16x8*>(&w0);
      const f16x8 pa1 = *reinterpret_cast<const f16x8*>(&w1);
      // ---- PV from swizzled Vt ----
      const char* vb = (const char*)&Vt[cur][0];
#pragma unroll
      for (int nd = 0; nd < 4; ++nd) {
        const int rowb = (nd * 16 + lr) * 128;
        const f16x8 bv0 = *reinterpret_cast<const f16x8*>(vb + rowb + xa);
        const f16x8 bv1 = *reinterpret_cast<const f16x8*>(vb + rowb + xb);
        acco[nd] = __builtin_amdgcn_mfma_f32_16x16x32_f16(pa0, bv0, acco[nd], 0, 0, 0);
        acco[nd] = __builtin_amdgcn_mfma_f32_16x16x32_f16(pa1, bv1, acco[nd], 0, 0, 0);
      }
      __syncthreads();   // reads of cur done + prefetch (vmcnt) drained
    }
    // ---- epilogue ----
    float lsq[4];
#pragma unroll
    for (int r = 0; r < 4; ++r) lsq[r] = __shfl(lsum, lh * 4 + r, 64);
#pragma unroll
    for (int nd = 0; nd < 4; ++nd)
#pragma unroll
      for (int r = 0; r < 4; ++r) {
        const float den = lsq[r];
        const float v = den > 0.f ? acco[nd][r] / den : 0.f;
        ctx[((long)b * kS + qbase + wave * 16 + lh * 4 + r) * kHID + h * 64 + nd * 16 + lr] =
            (_Float16)v;
      }
  }
}

// -------------------------------------------------------------- out GEMM ---
__global__ __launch_bounds__(256) void gemm_out(const _Float16* __restrict__ A,
                                                const _Float16* __restrict__ W,
                                                float* __restrict__ C,
                                                int M, int N, int K) {
  __shared__ __align__(16) _Float16 As[128 * 32];
  __shared__ __align__(16) _Float16 Bs[128 * 32];
  const int tid  = threadIdx.x;
  const int lane = tid & 63;
  const int wave = tid >> 6;
  const long bm = (long)blockIdx.y * 128;
  const long bn = (long)blockIdx.x * 128;
  const int wr = (wave >> 1) * 64;
  const int wc = (wave & 1) * 64;

  const int srow = wave * 32 + (lane >> 2);
  const int scol = (lane & 3) * 8;
  const _Float16* ga = A + (bm + srow) * (long)K + scol;
  const _Float16* gb = W + (bn + srow) * (long)K + scol;
  _Float16* lA0 = &As[wave * 1024];
  _Float16* lA1 = &As[wave * 1024 + 512];
  _Float16* lB0 = &Bs[wave * 1024];
  _Float16* lB1 = &Bs[wave * 1024 + 512];

  const int lr = lane & 15;
  const int lk = (lane >> 4) * 8;
  f32x4 acc[4][4] = {};

  for (int k0 = 0; k0 < K; k0 += 32) {
    GLD16(ga + k0, lA0);
    GLD16(ga + k0 + 16 * (long)K, lA1);
    GLD16(gb + k0, lB0);
    GLD16(gb + k0 + 16 * (long)K, lB1);
    __syncthreads();
    f16x8 af[4], bf[4];
#pragma unroll
    for (int i = 0; i < 4; ++i) {
      af[i] = *reinterpret_cast<const f16x8*>(&As[(wr + i * 16 + lr) * 32 + lk]);
      bf[i] = *reinterpret_cast<const f16x8*>(&Bs[(wc + i * 16 + lr) * 32 + lk]);
    }
#pragma unroll
    for (int i = 0; i < 4; ++i)
#pragma unroll
      for (int j = 0; j < 4; ++j)
        acc[i][j] = __builtin_amdgcn_mfma_f32_16x16x32_f16(af[i], bf[j], acc[i][j], 0, 0, 0);
    __syncthreads();
  }

  const int cr0 = wr + (lane >> 4) * 4;
  const int cc0 = wc + lr;
#pragma unroll
  for (int i = 0; i < 4; ++i)
#pragma unroll
    for (int j = 0; j < 4; ++j)
#pragma unroll
      for (int r = 0; r < 4; ++r)
        C[(bm + cr0 + i * 16 + r) * N + bn + cc0 + j * 16] = acc[i][j][r];
}

// ---------------------------------------------------------------- launch ----
extern "C" void kernel_launch(void* const* d_in, const int* in_sizes, int n_in,
                              void* d_out, int out_size, void* d_ws, size_t ws_size,
                              hipStream_t stream) {
  const float* x    = (const float*)d_in[0];
  const int*   mask = (const int*)d_in[1];
  const float* Wq   = (const float*)d_in[2];
  const float* Wk   = (const float*)d_in[3];
  const float* Wv   = (const float*)d_in[4];
  const float* Wo   = (const float*)d_in[5];
  const float* rel  = (const float*)d_in[6];
  float* out = (float*)d_out;

  const int M = kB * kS;          // 4096
  const int NX = M * kHID;        // 4,194,304
  const int NW = kHID * kHID;     // 1,048,576

  _Float16* ws   = (_Float16*)d_ws;
  _Float16* xh   = ws;
  _Float16* wqh  = xh + NX;       // wq,wk,wv,wo contiguous
  _Float16* woh  = wqh + 3 * NW;
  _Float16* Qh   = woh + NW;
  _Float16* Kh   = Qh + NX;
  _Float16* Vtg  = Kh + NX;       // [B][H][64][S] transposed V
  _Float16* ctxh = Vtg + NX;
  float*        maskbias  = (float*)(ctxh + NX);          // [B][S] f32
  unsigned int* tileflags = (unsigned int*)(maskbias + kB * kS);

  cvt_f32_f16<<<2048, 256, 0, stream>>>(x, xh, NX);
  cvt_w4<<<1024, 256, 0, stream>>>(Wq, Wk, Wv, Wo, wqh);
  prep_mask<<<kB, 256, 0, stream>>>(mask, maskbias, tileflags);

  gemm_qkv<<<dim3(24, 32), 256, 0, stream>>>(xh, wqh, Qh, Kh, Vtg);

  attn_fwd3<<<512, 256, 0, stream>>>(Qh, Kh, Vtg, maskbias, tileflags, rel, ctxh);

  gemm_out<<<dim3(8, 32), 256, 0, stream>>>(ctxh, woh, out, M, kHID, kHID);
}

// Round 7
// 201.202 us; speedup vs baseline: 1.9966x; 1.0991x over previous
//
#include <hip/hip_runtime.h>
#include <math.h>

// T5Attention forward, MI355X/gfx950.  Round 7:
//   prep_all (x+weights f32->f16, mask bitmask/bias) -- single launch
//   fused QKV GEMM (N=3072), V written TRANSPOSED [B][H][64][S]
//   flash attn: KVBLK=128, K+V swizzled global_load_lds double-buffer,
//     swapped QK^T, defer-max (THR=8), setprio around MFMA, XCD clustering
//   output GEMM 64x128 tiles (512 blocks, f32 out)

typedef float    f32x4 __attribute__((ext_vector_type(4)));
typedef _Float16 f16x8 __attribute__((ext_vector_type(8)));
typedef _Float16 f16x4 __attribute__((ext_vector_type(4)));

#define GLD16(gp, lp) __builtin_amdgcn_global_load_lds(                       \
    (const __attribute__((address_space(1))) void*)(gp),                      \
    (__attribute__((address_space(3))) void*)(lp), 16, 0, 0)

static constexpr int kB   = 2;
static constexpr int kS   = 2048;
static constexpr int kHID = 1024;
static constexpr int kH   = 16;

// ------------------------------------------------------------ prep (fused) --
// blocks [0,1024): x -> f16 ; [1024,2048): weights -> f16 ; [2048,2050): mask
__global__ __launch_bounds__(256) void prep_all(const float* __restrict__ x,
                                                const float* __restrict__ w0,
                                                const float* __restrict__ w1,
                                                const float* __restrict__ w2,
                                                const float* __restrict__ w3,
                                                const int* __restrict__ maskp,
                                                _Float16* __restrict__ xh,
                                                _Float16* __restrict__ wh,
                                                float* __restrict__ maskbias,
                                                unsigned int* __restrict__ tileflags) {
  const int bid = blockIdx.x, tid = threadIdx.x;
  if (bid < 2048) {
    const float* src;
    _Float16* dst;
    int base;
    if (bid < 1024) {
      src = x; dst = xh; base = bid * 4096;
    } else {
      const int wsel = (bid - 1024) >> 8;
      src = wsel == 0 ? w0 : wsel == 1 ? w1 : wsel == 2 ? w2 : w3;
      dst = wh + (long)wsel * 1048576;
      base = ((bid - 1024) & 255) * 4096;
    }
#pragma unroll
    for (int it = 0; it < 4; ++it) {
      const int i = base + it * 1024 + tid * 4;
      const float4 v = *reinterpret_cast<const float4*>(src + i);
      f16x4 o;
      o[0] = (_Float16)v.x; o[1] = (_Float16)v.y;
      o[2] = (_Float16)v.z; o[3] = (_Float16)v.w;
      *reinterpret_cast<f16x4*>(dst + i) = o;
    }
  } else {
    const int b = bid - 2048;
    const int wave = tid >> 6, lane = tid & 63;
    __shared__ unsigned int partial[4];
    unsigned int mybits = 0;
#pragma unroll
    for (int it = 0; it < 8; ++it) {
      const int t = it * 4 + wave;
      const int kp = t * 64 + lane;
      const int mv = maskp[b * kS + kp];
      maskbias[b * kS + kp] = mv ? 0.f : -INFINITY;
      const unsigned long long bal = __ballot(mv != 0);
      if (bal == ~0ull) mybits |= (1u << t);
    }
    if (lane == 0) partial[wave] = mybits;
    __syncthreads();
    if (tid == 0) tileflags[b] = partial[0] | partial[1] | partial[2] | partial[3];
  }
}

// ------------------------------------------------------- fused QKV GEMM ----
__global__ __launch_bounds__(256) void gemm_qkv(const _Float16* __restrict__ A,
                                                const _Float16* __restrict__ W,
                                                _Float16* __restrict__ Qh,
                                                _Float16* __restrict__ Kh,
                                                _Float16* __restrict__ Vtg) {
  constexpr int K = kHID;
  __shared__ __align__(16) _Float16 As[128 * 32];
  __shared__ __align__(16) _Float16 Bs[128 * 32];
  const int tid  = threadIdx.x;
  const int lane = tid & 63;
  const int wave = tid >> 6;
  const long bm = (long)blockIdx.y * 128;
  const long bn = (long)blockIdx.x * 128;
  const int wr = (wave >> 1) * 64;
  const int wc = (wave & 1) * 64;

  const int srow = wave * 32 + (lane >> 2);
  const int scol = (lane & 3) * 8;
  const _Float16* ga = A + (bm + srow) * (long)K + scol;
  const _Float16* gb = W + (bn + srow) * (long)K + scol;
  _Float16* lA0 = &As[wave * 1024];
  _Float16* lA1 = &As[wave * 1024 + 512];
  _Float16* lB0 = &Bs[wave * 1024];
  _Float16* lB1 = &Bs[wave * 1024 + 512];

  const int lr = lane & 15;
  const int lk = (lane >> 4) * 8;
  f32x4 acc[4][4] = {};

  for (int k0 = 0; k0 < K; k0 += 32) {
    GLD16(ga + k0, lA0);
    GLD16(ga + k0 + 16 * (long)K, lA1);
    GLD16(gb + k0, lB0);
    GLD16(gb + k0 + 16 * (long)K, lB1);
    __syncthreads();
    f16x8 af[4], bf[4];
#pragma unroll
    for (int i = 0; i < 4; ++i) {
      af[i] = *reinterpret_cast<const f16x8*>(&As[(wr + i * 16 + lr) * 32 + lk]);
      bf[i] = *reinterpret_cast<const f16x8*>(&Bs[(wc + i * 16 + lr) * 32 + lk]);
    }
#pragma unroll
    for (int i = 0; i < 4; ++i)
#pragma unroll
      for (int j = 0; j < 4; ++j)
        acc[i][j] = __builtin_amdgcn_mfma_f32_16x16x32_f16(af[i], bf[j], acc[i][j], 0, 0, 0);
    __syncthreads();
  }

  const int cr0 = wr + (lane >> 4) * 4;
  const int cc0 = wc + lr;
  const int cb = (int)(bn >> 10);          // 0=Q 1=K 2=V (block-uniform)
#pragma unroll
  for (int i = 0; i < 4; ++i)
#pragma unroll
    for (int j = 0; j < 4; ++j)
#pragma unroll
      for (int r = 0; r < 4; ++r) {
        const long row = bm + cr0 + i * 16 + r;       // token index
        const int  col = (int)bn + cc0 + j * 16;      // 0..3071
        const float v = acc[i][j][r];
        if (cb == 0) {
          Qh[row * kHID + col] = (_Float16)(v * 0.125f);
        } else if (cb == 1) {
          Kh[row * kHID + (col - 1024)] = (_Float16)v;
        } else {
          const int hid = col - 2048;
          const int hh = hid >> 6, dd = hid & 63;
          const int bb = (int)(row >> 11), sp = (int)(row & 2047);
          Vtg[((long)(bb * kH + hh) * 64 + dd) * kS + sp] = (_Float16)v;
        }
      }
}

// ---------------------------------------------------------- flash attention -
// 1D grid 512, block 256.  KVBLK=128.  XCD-clustered; q-tile pairs {i,31-i}
// -> uniform 17 128-kp tiles per block.
// K LDS [128][64] swizzled chunk c -> c^(kp&7); V LDS [64][128] swizzled
// chunk c -> c^(d&15).  Swapped QK^T; defer-max THR=8; setprio around MFMA.
__global__ __launch_bounds__(256) void attn_fwd4(const _Float16* __restrict__ Qh,
                                                 const _Float16* __restrict__ Kh,
                                                 const _Float16* __restrict__ Vtg,
                                                 const float* __restrict__ maskbias,
                                                 const unsigned int* __restrict__ tileflags,
                                                 const float* __restrict__ rel_emb,
                                                 _Float16* __restrict__ ctx) {
  __shared__ __align__(16) _Float16 Kt[2][128 * 64];
  __shared__ __align__(16) _Float16 Vt[2][64 * 128];
  __shared__ float bias_sh[32];

  const int tid  = threadIdx.x;
  const int lane = tid & 63;
  const int wave = tid >> 6;
  const int o = blockIdx.x;
  const int slot = o >> 3;
  const int p_ = (o & 7) + 8 * (slot >> 4);   // (b,h) group 0..31
  const int qp = slot & 15;                   // q pair 0..15
  const int b = p_ >> 4, h = p_ & 15;

  const int lr = lane & 15;
  const int lh = lane >> 4;

  if (tid < 32) bias_sh[tid] = rel_emb[tid * kH + h];
  const unsigned int flags = tileflags[b];

  // K staging (inst t=0..3): lane l -> LDS row wave*32+t*8+(l>>3), chunk l&7.
  const int kro = wave * 32 + (lane >> 3);
  const int kch = ((lane & 7) ^ (lane >> 3)) * 8;
  const _Float16* ksrcT[4];
#pragma unroll
  for (int t = 0; t < 4; ++t)
    ksrcT[t] = Kh + ((long)b * kS + kro + t * 8) * kHID + h * 64 + kch;
  // V staging (inst t=0..3): lane l -> LDS row wave*16+t*4+(l>>4), chunk l&15.
  const long bh64 = (long)(b * kH + h) * 64;
  const _Float16* vsrcT[4];
#pragma unroll
  for (int t = 0; t < 4; ++t) {
    const int d = wave * 16 + t * 4 + (lane >> 4);
    const int c = (lane & 15) ^ (d & 15);
    vsrcT[t] = Vtg + (bh64 + d) * kS + c * 8;
  }

  __syncthreads();  // bias_sh visible before first use

  for (int pass = 0; pass < 2; ++pass) {
    const int qt = (pass == 0) ? qp : 31 - qp;
    const int qbase = qt * 64;

    const long qrow = (long)b * kS + qbase + wave * 16 + lr;
    const f16x8 qf0 = *reinterpret_cast<const f16x8*>(&Qh[qrow * kHID + h * 64 + lh * 8]);
    const f16x8 qf1 = *reinterpret_cast<const f16x8*>(&Qh[qrow * kHID + h * 64 + 32 + lh * 8]);

    float m = -INFINITY, lsum = 0.f;
    f32x4 acco[4] = {};

    // prologue: stage tile 0 -> buf 0
#pragma unroll
    for (int t = 0; t < 4; ++t) {
      GLD16(ksrcT[t], &Kt[0][wave * 2048 + t * 512]);
      GLD16(vsrcT[t], &Vt[0][wave * 2048 + t * 512]);
    }
    __syncthreads();

    const int ntiles = (qt >> 1) + 1;
    for (int kt = 0; kt < ntiles; ++kt) {
      const int cur = kt & 1;
      const int kbase = kt * 128;
      if (kt + 1 < ntiles) {                 // prefetch next tile (async)
#pragma unroll
        for (int t = 0; t < 4; ++t) {
          GLD16(ksrcT[t] + (long)(kbase + 128) * kHID, &Kt[cur ^ 1][wave * 2048 + t * 512]);
          GLD16(vsrcT[t] + kbase + 128, &Vt[cur ^ 1][wave * 2048 + t * 512]);
        }
      }
      // ---- QK^T (swapped): sacc[nb] = S[kp=kbase+nb*16+lh*4+r][q] ----
      const char* kb_ = (const char*)&Kt[cur][0];
      const int xa = ((lh ^ (lr & 7)) << 4);
      const int xb = (((4 + lh) ^ (lr & 7)) << 4);
      f32x4 sacc[8] = {};
      __builtin_amdgcn_s_setprio(1);
#pragma unroll
      for (int nb = 0; nb < 8; ++nb) {
        const int rowb = (nb * 16 + lr) * 128;
        const f16x8 kf0 = *reinterpret_cast<const f16x8*>(kb_ + rowb + xa);
        const f16x8 kf1 = *reinterpret_cast<const f16x8*>(kb_ + rowb + xb);
        sacc[nb] = __builtin_amdgcn_mfma_f32_16x16x32_f16(kf0, qf0, sacc[nb], 0, 0, 0);
        sacc[nb] = __builtin_amdgcn_mfma_f32_16x16x32_f16(kf1, qf1, sacc[nb], 0, 0, 0);
      }
      __builtin_amdgcn_s_setprio(0);

      const int q = qbase + wave * 16 + lr;
      const bool tilevalid = ((flags >> (2 * kt)) & 3u) == 3u;
      const bool fast = tilevalid && (kbase + 142 <= qbase);

      if (fast) {
        // bias is uniformly bias_sh[31]; fold into m.
        const float b31 = bias_sh[31];
        float pmax = sacc[0][0];
#pragma unroll
        for (int nb = 0; nb < 8; ++nb)
#pragma unroll
          for (int r = 0; r < 4; ++r) pmax = fmaxf(pmax, sacc[nb][r]);
        float mb = m - b31;
        if (!__all(pmax <= mb + 8.f)) {
          float tmax = fmaxf(pmax, __shfl_xor(pmax, 16, 64));
          tmax = fmaxf(tmax, __shfl_xor(tmax, 32, 64));
          const float mnew = fmaxf(m, tmax + b31);
          const float alpha = __expf(m - mnew);     // m finite here (past tiles)
          lsum *= alpha;
          float alq[4];
#pragma unroll
          for (int r = 0; r < 4; ++r) alq[r] = __shfl(alpha, lh * 4 + r, 64);
#pragma unroll
          for (int nd = 0; nd < 4; ++nd) {
            acco[nd][0] *= alq[0]; acco[nd][1] *= alq[1];
            acco[nd][2] *= alq[2]; acco[nd][3] *= alq[3];
          }
          m = mnew;
          mb = m - b31;
        }
        float rs = 0.f;
#pragma unroll
        for (int nb = 0; nb < 8; ++nb)
#pragma unroll
          for (int r = 0; r < 4; ++r) {
            const float pv = __expf(sacc[nb][r] - mb);
            sacc[nb][r] = pv;
            rs += pv;
          }
        rs += __shfl_xor(rs, 16, 64);
        rs += __shfl_xor(rs, 32, 64);
        lsum += rs;
      } else {
        float pmax = -INFINITY;
#pragma unroll
        for (int nb = 0; nb < 8; ++nb)
#pragma unroll
          for (int r = 0; r < 4; ++r) {
            const int kp = kbase + nb * 16 + lh * 4 + r;
            const float mbv = tilevalid ? 0.f : maskbias[b * kS + kp];
            int d = q - kp;
            d = d > 15 ? 15 : d;
            d = d < -16 ? -16 : d;
            const float s = sacc[nb][r] + bias_sh[d + 16] + mbv;
            sacc[nb][r] = (kp <= q) ? s : -INFINITY;
            pmax = fmaxf(pmax, sacc[nb][r]);
          }
        if (!__all(pmax <= m + 8.f)) {
          float tmax = fmaxf(pmax, __shfl_xor(pmax, 16, 64));
          tmax = fmaxf(tmax, __shfl_xor(tmax, 32, 64));
          const float mnew = fmaxf(m, tmax);
          const float alpha = (mnew == -INFINITY) ? 1.f : __expf(m - mnew);
          lsum *= alpha;
          float alq[4];
#pragma unroll
          for (int r = 0; r < 4; ++r) alq[r] = __shfl(alpha, lh * 4 + r, 64);
#pragma unroll
          for (int nd = 0; nd < 4; ++nd) {
            acco[nd][0] *= alq[0]; acco[nd][1] *= alq[1];
            acco[nd][2] *= alq[2]; acco[nd][3] *= alq[3];
          }
          m = mnew;
        }
        float rs = 0.f;
#pragma unroll
        for (int nb = 0; nb < 8; ++nb)
#pragma unroll
          for (int r = 0; r < 4; ++r) {
            const float pv = (sacc[nb][r] == -INFINITY) ? 0.f : __expf(sacc[nb][r] - m);
            sacc[nb][r] = pv;
            rs += pv;
          }
        rs += __shfl_xor(rs, 16, 64);
        rs += __shfl_xor(rs, 32, 64);
        lsum += rs;
      }

      // ---- pack P -> fp16 A-frags (4 frags, validated shfl pattern) ----
      int pk[8][2];
#pragma unroll
      for (int nb = 0; nb < 8; ++nb) {
        pk[nb][0] = __builtin_bit_cast(int, __builtin_amdgcn_cvt_pkrtz(sacc[nb][0], sacc[nb][1]));
        pk[nb][1] = __builtin_bit_cast(int, __builtin_amdgcn_cvt_pkrtz(sacc[nb][2], sacc[nb][3]));
      }
      const int srcA = (((lh * 2) & 3) << 4) | lr;
      const int srcB = (((lh * 2 + 1) & 3) << 4) | lr;
      const bool lo = lh < 2;
      int4 wv[4];
#pragma unroll
      for (int s = 0; s < 4; ++s) {
        const int a0 = __shfl(pk[2 * s][0], srcA, 64), b0 = __shfl(pk[2 * s + 1][0], srcA, 64);
        const int a1 = __shfl(pk[2 * s][1], srcA, 64), b1 = __shfl(pk[2 * s + 1][1], srcA, 64);
        const int a2 = __shfl(pk[2 * s][0], srcB, 64), b2 = __shfl(pk[2 * s + 1][0], srcB, 64);
        const int a3 = __shfl(pk[2 * s][1], srcB, 64), b3 = __shfl(pk[2 * s + 1][1], srcB, 64);
        wv[s].x = lo ? a0 : b0; wv[s].y = lo ? a1 : b1;
        wv[s].z = lo ? a2 : b2; wv[s].w = lo ? a3 : b3;
      }
      // ---- PV from swizzled Vt: B row d=nd*16+lr, chunk (s*4+lh)^lr ----
      const char* vb = (const char*)&Vt[cur][0];
      __builtin_amdgcn_s_setprio(1);
#pragma unroll
      for (int s = 0; s < 4; ++s) {
        const f16x8 pa = *reinterpret_cast<const f16x8*>(&wv[s]);
#pragma unroll
        for (int nd = 0; nd < 4; ++nd) {
          const int rowb = (nd * 16 + lr) * 256;
          const f16x8 bv = *reinterpret_cast<const f16x8*>(vb + rowb + ((((s * 4) + lh) ^ lr) << 4));
          acco[nd] = __builtin_amdgcn_mfma_f32_16x16x32_f16(pa, bv, acco[nd], 0, 0, 0);
        }
      }
      __builtin_amdgcn_s_setprio(0);
      __syncthreads();   // reads of cur done + prefetch drained
    }
    // ---- epilogue ----
    float lsq[4];
#pragma unroll
    for (int r = 0; r < 4; ++r) lsq[r] = __shfl(lsum, lh * 4 + r, 64);
#pragma unroll
    for (int nd = 0; nd < 4; ++nd)
#pragma unroll
      for (int r = 0; r < 4; ++r) {
        const float den = lsq[r];
        const float v = den > 0.f ? acco[nd][r] / den : 0.f;
        ctx[((long)b * kS + qbase + wave * 16 + lh * 4 + r) * kHID + h * 64 + nd * 16 + lr] =
            (_Float16)v;
      }
  }
}

// -------------------------------------------------------------- out GEMM ---
// 64x128 tile (M x N), 4 waves 2x2 of 32x64, grid (N/128, M/64) = (8,64).
__global__ __launch_bounds__(256) void gemm_out(const _Float16* __restrict__ A,
                                                const _Float16* __restrict__ W,
                                                float* __restrict__ C,
                                                int M, int N, int K) {
  __shared__ __align__(16) _Float16 As[64 * 32];
  __shared__ __align__(16) _Float16 Bs[128 * 32];
  const int tid  = threadIdx.x;
  const int lane = tid & 63;
  const int wave = tid >> 6;
  const long bm = (long)blockIdx.y * 64;
  const long bn = (long)blockIdx.x * 128;
  const int wr = (wave >> 1) * 32;
  const int wc = (wave & 1) * 64;

  const int srowA = wave * 16 + (lane >> 2);
  const int srowB = wave * 32 + (lane >> 2);
  const int scol = (lane & 3) * 8;
  const _Float16* ga = A + (bm + srowA) * (long)K + scol;
  const _Float16* gb = W + (bn + srowB) * (long)K + scol;
  _Float16* lA0 = &As[wave * 512];
  _Float16* lB0 = &Bs[wave * 1024];
  _Float16* lB1 = &Bs[wave * 1024 + 512];

  const int lr = lane & 15;
  const int lk = (lane >> 4) * 8;
  f32x4 acc[2][4] = {};

  for (int k0 = 0; k0 < K; k0 += 32) {
    GLD16(ga + k0, lA0);
    GLD16(gb + k0, lB0);
    GLD16(gb + k0 + 16 * (long)K, lB1);
    __syncthreads();
    f16x8 af[2], bf[4];
#pragma unroll
    for (int i = 0; i < 2; ++i)
      af[i] = *reinterpret_cast<const f16x8*>(&As[(wr + i * 16 + lr) * 32 + lk]);
#pragma unroll
    for (int j = 0; j < 4; ++j)
      bf[j] = *reinterpret_cast<const f16x8*>(&Bs[(wc + j * 16 + lr) * 32 + lk]);
#pragma unroll
    for (int i = 0; i < 2; ++i)
#pragma unroll
      for (int j = 0; j < 4; ++j)
        acc[i][j] = __builtin_amdgcn_mfma_f32_16x16x32_f16(af[i], bf[j], acc[i][j], 0, 0, 0);
    __syncthreads();
  }

  const int cr0 = wr + (lane >> 4) * 4;
  const int cc0 = wc + lr;
#pragma unroll
  for (int i = 0; i < 2; ++i)
#pragma unroll
    for (int j = 0; j < 4; ++j)
#pragma unroll
      for (int r = 0; r < 4; ++r)
        C[(bm + cr0 + i * 16 + r) * N + bn + cc0 + j * 16] = acc[i][j][r];
}

// ---------------------------------------------------------------- launch ----
extern "C" void kernel_launch(void* const* d_in, const int* in_sizes, int n_in,
                              void* d_out, int out_size, void* d_ws, size_t ws_size,
                              hipStream_t stream) {
  const float* x    = (const float*)d_in[0];
  const int*   mask = (const int*)d_in[1];
  const float* Wq   = (const float*)d_in[2];
  const float* Wk   = (const float*)d_in[3];
  const float* Wv   = (const float*)d_in[4];
  const float* Wo   = (const float*)d_in[5];
  const float* rel  = (const float*)d_in[6];
  float* out = (float*)d_out;

  const int M = kB * kS;          // 4096
  const int NX = M * kHID;        // 4,194,304
  const int NW = kHID * kHID;     // 1,048,576

  _Float16* ws   = (_Float16*)d_ws;
  _Float16* xh   = ws;
  _Float16* wqh  = xh + NX;       // wq,wk,wv,wo contiguous
  _Float16* woh  = wqh + 3 * NW;
  _Float16* Qh   = woh + NW;
  _Float16* Kh   = Qh + NX;
  _Float16* Vtg  = Kh + NX;       // [B][H][64][S] transposed V
  _Float16* ctxh = Vtg + NX;
  float*        maskbias  = (float*)(ctxh + NX);          // [B][S] f32
  unsigned int* tileflags = (unsigned int*)(maskbias + kB * kS);

  prep_all<<<2050, 256, 0, stream>>>(x, Wq, Wk, Wv, Wo, mask, xh, wqh,
                                     maskbias, tileflags);

  gemm_qkv<<<dim3(24, 32), 256, 0, stream>>>(xh, wqh, Qh, Kh, Vtg);

  attn_fwd4<<<512, 256, 0, stream>>>(Qh, Kh, Vtg, maskbias, tileflags, rel, ctxh);

  gemm_out<<<dim3(8, 64), 256, 0, stream>>>(ctxh, woh, out, M, kHID, kHID);
}